// Round 19
// baseline (90.805 us; speedup 1.0000x reference)
//
#include <hip/hip_runtime.h>
#include <math.h>

// Problem constants
#define S_ 2048
#define D_ 256
#define B_ 4
#define H_ 4
// M = B*S = 8192, DH = 64

typedef __attribute__((ext_vector_type(8))) short  bh8;   // 8 bf16 (4 VGPR)
typedef __attribute__((ext_vector_type(4))) float  fx4;
typedef __attribute__((ext_vector_type(4))) unsigned short us4;
typedef __attribute__((ext_vector_type(4))) unsigned int   ux4;

__device__ inline unsigned short bf16r(float f) {
    unsigned int u = __builtin_bit_cast(unsigned int, f);
    return (unsigned short)((u + 0x7FFFu + ((u >> 16) & 1u)) >> 16);
}
// v_cvt_pk_bf16_f32: src0 -> low bf16, src1 -> high bf16 (T12 recipe)
__device__ inline unsigned int cvtpk(float a, float b) {
    unsigned int r;
    asm("v_cvt_pk_bf16_f32 %0, %1, %2" : "=v"(r) : "v"(a), "v"(b));
    return r;
}
// raw hardware exp2 (scores bounded; masked -> exp2(-1e9) = 0 in HW).
// VOLATILE: R16 showed the scheduler hurts when free to reorder.
__device__ inline float vexp2(float x) {
    float r;
    asm volatile("v_exp_f32 %0, %1\n\ts_nop 1" : "=v"(r) : "v"(x));
    return r;
}

// ---------------------------------------------------------------------------
// MFMA-fragment-order layout [verified R13-R15]. X[m][k] of [Mtot][K] at:
//   ((m/16)*K32 + k/32)*512 + (((k%32)/8)*16 + m%16)*8 + k%8,  K32 = K/32.
// One wave-load at (mtile*K32+kt)*512 + lane*8 fetches a 16x32 A/B fragment.
// ---------------------------------------------------------------------------
__device__ inline size_t fragoff(int m, int k, int K32) {
    return ((size_t)(m >> 4) * K32 + (k >> 5)) * 512
         + (size_t)((((k >> 3) & 3) * 16 + (m & 15)) * 8 + (k & 7));
}

// ---------------------------------------------------------------------------
// Fused prep: ALL weights + xb -> bf16 FRAG order; maskf.
// ---------------------------------------------------------------------------
__global__ __launch_bounds__(256) void prep_all_k(
    const float* __restrict__ qkv_w, const float* __restrict__ proj_w,
    const float* __restrict__ w1,    const float* __restrict__ w2,
    unsigned short* __restrict__ qkv_wf, unsigned short* __restrict__ proj_wf,
    unsigned short* __restrict__ w1f,    unsigned short* __restrict__ w2f,
    const float* __restrict__ x,
    const float* __restrict__ g1, const float* __restrict__ b1,
    const float* __restrict__ m1, const float* __restrict__ v1,
    unsigned short* __restrict__ xbf,
    const int* __restrict__ mask, float* __restrict__ maskf)
{
    const int bidx = blockIdx.x;
    if (bidx < 768) {
        const float* W; unsigned short* Wt; int K, N, u0;
        if (bidx < 192)      { W = qkv_w;  Wt = qkv_wf;  K = 256;  N = 768;  u0 = bidx * 256; }
        else if (bidx < 256) { W = proj_w; Wt = proj_wf; K = 256;  N = 256;  u0 = (bidx - 192) * 256; }
        else if (bidx < 512) { W = w1;     Wt = w1f;     K = 256;  N = 1024; u0 = (bidx - 256) * 256; }
        else                 { W = w2;     Wt = w2f;     K = 1024; N = 256;  u0 = (bidx - 512) * 256; }
        const int u = u0 + threadIdx.x;
        const int k4 = u / N, n = u % N;
        us4 tv;
        #pragma unroll
        for (int j = 0; j < 4; ++j) tv[j] = bf16r(W[(size_t)(k4 * 4 + j) * N + n]);
        *(us4*)&Wt[fragoff(n, k4 * 4, K >> 5)] = tv;
    } else if (bidx < 2816) {
        const int i = (bidx - 768) * 256 + threadIdx.x;   // us4 unit
        const int m = i >> 6, c0 = (i & 63) * 4;
        float4 xv = *(const float4*)&x[(size_t)i * 4];
        float vv[4] = {xv.x, xv.y, xv.z, xv.w};
        us4 tv;
        #pragma unroll
        for (int j = 0; j < 4; ++j) {
            int c = c0 + j;
            float s = g1[c] * rsqrtf(v1[c] + 1e-3f);
            tv[j] = bf16r(vv[j] * s + (b1[c] - m1[c] * s));
        }
        *(us4*)&xbf[fragoff(m, c0, 8)] = tv;
    } else {
        const int i = (bidx - 2816) * 256 + threadIdx.x;
        maskf[i] = mask[i] ? 0.0f : -1e9f;
    }
}

// ---------------------------------------------------------------------------
// qkv GEMM, frag-streaming (fused-MLP style): block = 16-row stripe, 8 waves,
// NO LDS, NO barriers. Wave w owns n-cols [w*96, w*96+96) = 6 n-tiles.
// Per kt: 1 A-frag + 6 B-frags + 6 MFMAs. Epilogue -> frag qf/kf/vf
// (q scaled by D^-0.5 * log2e). Grid 512 stripes.
// ---------------------------------------------------------------------------
__global__ __launch_bounds__(512) void gemm_qkv_frag_k(
    const unsigned short* __restrict__ xbf, const unsigned short* __restrict__ Wf,
    unsigned short* __restrict__ qf_o, unsigned short* __restrict__ kf_o,
    unsigned short* __restrict__ vf_o)
{
    const int t = threadIdx.x, w = t >> 6, l = t & 63;
    const int qi = l & 15, g = l >> 4;
    const int mt = blockIdx.x;                 // 16-row stripe
    const int nt0 = w * 6;                     // first n-tile of this wave

    fx4 acc[6];
    #pragma unroll
    for (int j = 0; j < 6; ++j) acc[j] = (fx4){0.f, 0.f, 0.f, 0.f};

    const unsigned short* Ab = xbf + (size_t)mt * 8 * 512 + l * 8;
    const unsigned short* Bb = Wf + (size_t)nt0 * 8 * 512 + l * 8;

    #pragma unroll
    for (int kt = 0; kt < 8; ++kt) {
        bh8 a = *(const bh8*)(Ab + (size_t)kt * 512);
        #pragma unroll
        for (int j = 0; j < 6; ++j) {
            bh8 b = *(const bh8*)(Bb + ((size_t)j * 8 + kt) * 512);
            acc[j] = __builtin_amdgcn_mfma_f32_16x16x32_bf16(a, b, acc[j], 0, 0, 0);
        }
    }

    // epilogue: row = mt*16 + g*4 + r, col nf = (nt0+j)*16 (+qi)
    #pragma unroll
    for (int j = 0; j < 6; ++j) {
        const int nf = (nt0 + j) * 16;
        const int h = nf / 192, rem = nf % 192;
        const int region = rem / 64;
        const int c = rem % 64 + qi;          // head-local column (dim)
        #pragma unroll
        for (int r = 0; r < 4; ++r) {
            const int m = mt * 16 + g * 4 + r;
            const int s = m & 2047;
            const size_t bh = (size_t)((m >> 11) * 4 + h);
            float a = acc[j][r];
            if (region < 2) {
                size_t off = (((bh * 128 + (s >> 4)) * 2 + (c >> 5)) * 64
                              + ((c >> 3) & 3) * 16 + (s & 15)) * 8 + (c & 7);
                if (region == 0)
                    qf_o[off] = bf16r(a * (0.0625f * 1.44269504f));
                else
                    kf_o[off] = bf16r(a);
            } else {
                size_t off = ((((bh * 32 + (s >> 6)) * 4 + (c >> 4)) * 2
                              + ((s >> 5) & 1)) * 64
                              + ((s >> 3) & 3) * 16 + (c & 15)) * 8 + (s & 7);
                vf_o[off] = bf16r(a);
            }
        }
    }
}

// ---------------------------------------------------------------------------
// Fused MLP block [FROZEN @ R18]: proj(+x, BN2) -> mlp1(swish) -> mlp2(+x2).
// One block = one 16-row stripe (grid 512), 8 waves. x2 residual in REGISTERS;
// x2nb/h2 in LDS frag order; weights stream from global frag order.
// ---------------------------------------------------------------------------
__global__ __launch_bounds__(512) void fused_mlp_k(
    const unsigned short* __restrict__ ob,       // frag, A of proj (K32=8)
    const unsigned short* __restrict__ proj_wf,  // frag by n (K32=8)
    const unsigned short* __restrict__ w1f,      // frag by n (K32=8)
    const unsigned short* __restrict__ w2f,      // frag by n (K32=32)
    const float* __restrict__ x,
    const float* __restrict__ g2, const float* __restrict__ b2,
    const float* __restrict__ m2, const float* __restrict__ v2,
    float* __restrict__ out)
{
    __shared__ unsigned short x2nb[8 * 512];    // 16x256 bf16, frag order
    __shared__ unsigned short h2[32 * 512];     // 16x1024 bf16, frag order

    const int t = threadIdx.x, w = t >> 6, l = t & 63;
    const int qi = l & 15, g = l >> 4;
    const int mt = blockIdx.x;                  // 16-row stripe
    const int m0 = mt * 16;

    // ---- phase 1: proj (K=256, wave cols [w*32, w*32+32)) ----
    fx4 acc1[2];
    acc1[0] = (fx4){0.f, 0.f, 0.f, 0.f};
    acc1[1] = (fx4){0.f, 0.f, 0.f, 0.f};
    {
        const unsigned short* Ab = ob + (size_t)mt * 8 * 512 + l * 8;
        const unsigned short* B0 = proj_wf + ((size_t)(w * 2 + 0) * 8) * 512 + l * 8;
        const unsigned short* B1 = proj_wf + ((size_t)(w * 2 + 1) * 8) * 512 + l * 8;
        #pragma unroll
        for (int kt = 0; kt < 8; ++kt) {
            bh8 a  = *(const bh8*)(Ab + (size_t)kt * 512);
            bh8 b0 = *(const bh8*)(B0 + (size_t)kt * 512);
            bh8 b1 = *(const bh8*)(B1 + (size_t)kt * 512);
            acc1[0] = __builtin_amdgcn_mfma_f32_16x16x32_bf16(a, b0, acc1[0], 0, 0, 0);
            acc1[1] = __builtin_amdgcn_mfma_f32_16x16x32_bf16(a, b1, acc1[1], 0, 0, 0);
        }
    }
    float x2res[2][4];
    #pragma unroll
    for (int nt = 0; nt < 2; ++nt) {
        const int n = w * 32 + nt * 16 + qi;
        const float s2 = g2[n] * rsqrtf(v2[n] + 1e-3f);
        const float o2 = b2[n] - m2[n] * s2;
        #pragma unroll
        for (int r = 0; r < 4; ++r) {
            const int m = m0 + g * 4 + r;
            float rv = acc1[nt][r] + x[(size_t)m * 256 + n];
            x2res[nt][r] = rv;
            x2nb[w * 512 + ((nt * 2 + (qi >> 3)) * 16 + g * 4 + r) * 8 + (qi & 7)]
                = bf16r(rv * s2 + o2);
        }
    }
    __syncthreads();

    // ---- phase 2: mlp1 (K=256, wave cols [w*128, w*128+128)) ----
    fx4 acc2[8];
    #pragma unroll
    for (int nt = 0; nt < 8; ++nt) acc2[nt] = (fx4){0.f, 0.f, 0.f, 0.f};
    {
        #pragma unroll
        for (int kt = 0; kt < 8; ++kt) {
            bh8 a = *(const bh8*)&x2nb[kt * 512 + l * 8];
            #pragma unroll
            for (int nt = 0; nt < 8; ++nt) {
                bh8 b = *(const bh8*)(w1f + ((size_t)(w * 8 + nt) * 8 + kt) * 512 + l * 8);
                acc2[nt] = __builtin_amdgcn_mfma_f32_16x16x32_bf16(a, b, acc2[nt], 0, 0, 0);
            }
        }
    }
    __syncthreads();   // all phase-2 x2nb reads done (x2nb dead now)
    #pragma unroll
    for (int nt = 0; nt < 8; ++nt) {
        #pragma unroll
        for (int r = 0; r < 4; ++r) {
            const int n = w * 128 + nt * 16 + qi;
            float a = acc2[nt][r];
            float hv = a / (1.0f + __expf(-a));
            h2[(n >> 5) * 512 + (((n >> 3) & 3) * 16 + g * 4 + r) * 8 + (n & 7)]
                = bf16r(hv);
        }
    }
    __syncthreads();

    // ---- phase 3: mlp2 (K=1024, wave cols [w*32, w*32+32)) ----
    fx4 acc3[2];
    acc3[0] = (fx4){0.f, 0.f, 0.f, 0.f};
    acc3[1] = (fx4){0.f, 0.f, 0.f, 0.f};
    {
        const unsigned short* B0 = w2f + ((size_t)(w * 2 + 0) * 32) * 512 + l * 8;
        const unsigned short* B1 = w2f + ((size_t)(w * 2 + 1) * 32) * 512 + l * 8;
        #pragma unroll 4
        for (int kt = 0; kt < 32; ++kt) {
            bh8 a  = *(const bh8*)&h2[kt * 512 + l * 8];
            bh8 b0 = *(const bh8*)(B0 + (size_t)kt * 512);
            bh8 b1 = *(const bh8*)(B1 + (size_t)kt * 512);
            acc3[0] = __builtin_amdgcn_mfma_f32_16x16x32_bf16(a, b0, acc3[0], 0, 0, 0);
            acc3[1] = __builtin_amdgcn_mfma_f32_16x16x32_bf16(a, b1, acc3[1], 0, 0, 0);
        }
    }
    #pragma unroll
    for (int nt = 0; nt < 2; ++nt) {
        #pragma unroll
        for (int r = 0; r < 4; ++r) {
            const int m = m0 + g * 4 + r;
            const int n = w * 32 + nt * 16 + qi;
            out[(size_t)m * 256 + n] = acc3[nt][r] + x2res[nt][r];
        }
    }
}

// ---------------------------------------------------------------------------
// MFMA flash attention [FROZEN @ R14/R18, 43.0 us]: 2 Q-subtiles per wave,
// 2-way key split, volatile vexp2 fixed-max softmax, frag Q/K/V, frag ob.
// Grid 512: bid&15 = (b,h) -> XCD-local KV.
// ---------------------------------------------------------------------------
__global__ __launch_bounds__(256) void attn_mfma_k(
    const unsigned short* __restrict__ qf,
    const unsigned short* __restrict__ kf,
    const unsigned short* __restrict__ vf,
    const float* __restrict__ maskf,
    unsigned short* __restrict__ ob)
{
    __shared__ fx4  Ol[2][64][8];
    __shared__ float Ll[2][64][2];

    const int bid = blockIdx.x;
    const int bh = bid & 15, qt = bid >> 4;        // qt in [0,32): 64 q-rows
    const int b = bh >> 2, h = bh & 3;
    const int t = threadIdx.x;
    const int w = t >> 6, lane = t & 63;
    const int g = lane >> 4, qi = lane & 15;
    const int qh = w & 1;                          // 32-row group within block
    const int khalf = w >> 1;                      // key half

    bh8 qA0, qA1, qB0, qB1;
    {
        const unsigned short* qp =
            qf + (size_t)(bh * 128 + qt * 4 + qh * 2) * 1024 + lane * 8;
        qA0 = *(const bh8*)(qp);
        qA1 = *(const bh8*)(qp + 512);
        qB0 = *(const bh8*)(qp + 1024);
        qB1 = *(const bh8*)(qp + 1536);
    }

    fx4 oA[4], oB[4];
    #pragma unroll
    for (int dt = 0; dt < 4; ++dt) {
        oA[dt] = (fx4){0.f, 0.f, 0.f, 0.f};
        oB[dt] = (fx4){0.f, 0.f, 0.f, 0.f};
    }
    float lsA = 0.f, lsB = 0.f;

    const unsigned short* kcur = kf + (size_t)bh * 131072 + khalf * 65536 + lane * 8;
    const unsigned short* vcur = vf + (size_t)bh * 131072 + khalf * 65536 + lane * 8;
    const float* mcur = maskf + b * 2048 + khalf * 1024 + g * 4;

    bh8 kfA[4][2], kfB[4][2], afA[4][2], afB[4][2];
    fx4 mvA[4], mvB[4];

#define LOADK(KF, MV) {                                                       \
    KF[0][0] = *(const bh8*)(kcur);        KF[0][1] = *(const bh8*)(kcur + 512);  \
    KF[1][0] = *(const bh8*)(kcur + 1024); KF[1][1] = *(const bh8*)(kcur + 1536); \
    KF[2][0] = *(const bh8*)(kcur + 2048); KF[2][1] = *(const bh8*)(kcur + 2560); \
    KF[3][0] = *(const bh8*)(kcur + 3072); KF[3][1] = *(const bh8*)(kcur + 3584); \
    MV[0] = *(const fx4*)(mcur);      MV[1] = *(const fx4*)(mcur + 16);       \
    MV[2] = *(const fx4*)(mcur + 32); MV[3] = *(const fx4*)(mcur + 48);       \
    kcur += 4096; mcur += 64; }

#define LOADV(AF) {                                                           \
    AF[0][0] = *(const bh8*)(vcur);        AF[0][1] = *(const bh8*)(vcur + 512);  \
    AF[1][0] = *(const bh8*)(vcur + 1024); AF[1][1] = *(const bh8*)(vcur + 1536); \
    AF[2][0] = *(const bh8*)(vcur + 2048); AF[2][1] = *(const bh8*)(vcur + 2560); \
    AF[3][0] = *(const bh8*)(vcur + 3072); AF[3][1] = *(const bh8*)(vcur + 3584); \
    vcur += 4096; }

#define PROCESS(KF, AF, MV) {                                                 \
    fx4 sA[4], sB[4];                                                         \
    _Pragma("unroll")                                                         \
    for (int kt = 0; kt < 4; ++kt) {                                          \
        fx4 zA = MV[kt];                                                      \
        zA = __builtin_amdgcn_mfma_f32_16x16x32_bf16(KF[kt][0], qA0, zA, 0, 0, 0); \
        zA = __builtin_amdgcn_mfma_f32_16x16x32_bf16(KF[kt][1], qA1, zA, 0, 0, 0); \
        sA[kt] = zA;                                                          \
        fx4 zB = MV[kt];                                                      \
        zB = __builtin_amdgcn_mfma_f32_16x16x32_bf16(KF[kt][0], qB0, zB, 0, 0, 0); \
        zB = __builtin_amdgcn_mfma_f32_16x16x32_bf16(KF[kt][1], qB1, zB, 0, 0, 0); \
        sB[kt] = zB;                                                          \
    }                                                                         \
    unsigned int pkA[4][2], pkB[4][2];                                        \
    _Pragma("unroll")                                                         \
    for (int kt = 0; kt < 4; ++kt) {                                          \
        float a0 = vexp2(sA[kt][0]);                                          \
        float a1 = vexp2(sA[kt][1]);                                          \
        float a2 = vexp2(sA[kt][2]);                                          \
        float a3 = vexp2(sA[kt][3]);                                          \
        lsA += (a0 + a1) + (a2 + a3);                                         \
        pkA[kt][0] = cvtpk(a0, a1);                                           \
        pkA[kt][1] = cvtpk(a2, a3);                                           \
        float b0 = vexp2(sB[kt][0]);                                          \
        float b1 = vexp2(sB[kt][1]);                                          \
        float b2 = vexp2(sB[kt][2]);                                          \
        float b3 = vexp2(sB[kt][3]);                                          \
        lsB += (b0 + b1) + (b2 + b3);                                         \
        pkB[kt][0] = cvtpk(b0, b1);                                           \
        pkB[kt][1] = cvtpk(b2, b3);                                           \
    }                                                                         \
    _Pragma("unroll")                                                         \
    for (int c = 0; c < 2; ++c) {                                             \
        unsigned int bwA[4], bwB[4];                                          \
        _Pragma("unroll")                                                     \
        for (int wd = 0; wd < 4; ++wd) {                                      \
            int src = (2 * (g & 1) + (wd >> 1)) * 16 + qi;                    \
            unsigned int vaA = (unsigned int)__shfl((int)pkA[2 * c][wd & 1], src, 64);     \
            unsigned int vbA = (unsigned int)__shfl((int)pkA[2 * c + 1][wd & 1], src, 64); \
            bwA[wd] = (g >= 2) ? vbA : vaA;                                   \
            unsigned int vaB = (unsigned int)__shfl((int)pkB[2 * c][wd & 1], src, 64);     \
            unsigned int vbB = (unsigned int)__shfl((int)pkB[2 * c + 1][wd & 1], src, 64); \
            bwB[wd] = (g >= 2) ? vbB : vaB;                                   \
        }                                                                     \
        bh8 bfA = __builtin_bit_cast(bh8, (ux4){bwA[0], bwA[1], bwA[2], bwA[3]}); \
        bh8 bfB = __builtin_bit_cast(bh8, (ux4){bwB[0], bwB[1], bwB[2], bwB[3]}); \
        _Pragma("unroll")                                                     \
        for (int dt = 0; dt < 4; ++dt) {                                      \
            oA[dt] = __builtin_amdgcn_mfma_f32_16x16x32_bf16(AF[dt][c], bfA, oA[dt], 0, 0, 0); \
            oB[dt] = __builtin_amdgcn_mfma_f32_16x16x32_bf16(AF[dt][c], bfB, oB[dt], 0, 0, 0); \
        }                                                                     \
    } }

    LOADK(kfA, mvA);
    LOADV(afA);
    for (int it = 0; it < 16; it += 2) {
        LOADK(kfB, mvB);
        LOADV(afB);
        PROCESS(kfA, afA, mvA);
        if (it + 2 < 16) {
            LOADK(kfA, mvA);
            LOADV(afA);
        }
        PROCESS(kfB, afB, mvB);
    }
#undef LOADK
#undef LOADV
#undef PROCESS

    // ---- combine key-halves: waves 2,3 publish; waves 0,1 add + write
    const int slot = w & 1;
    if (w >= 2) {
        #pragma unroll
        for (int dt = 0; dt < 4; ++dt) {
            Ol[slot][lane][dt]     = oA[dt];
            Ol[slot][lane][4 + dt] = oB[dt];
        }
        Ll[slot][lane][0] = lsA;
        Ll[slot][lane][1] = lsB;
    }
    __syncthreads();
    if (w < 2) {
        lsA += Ll[slot][lane][0];
        lsB += Ll[slot][lane][1];
        #pragma unroll
        for (int dt = 0; dt < 4; ++dt) {
            fx4 pa = Ol[slot][lane][dt], pb = Ol[slot][lane][4 + dt];
            oA[dt][0] += pa[0]; oA[dt][1] += pa[1]; oA[dt][2] += pa[2]; oA[dt][3] += pa[3];
            oB[dt][0] += pb[0]; oB[dt][1] += pb[1]; oB[dt][2] += pb[2]; oB[dt][3] += pb[3];
        }
        lsA += __shfl_xor(lsA, 16, 64);
        lsA += __shfl_xor(lsA, 32, 64);
        lsB += __shfl_xor(lsB, 16, 64);
        lsB += __shfl_xor(lsB, 32, 64);
        float invA = 1.0f / lsA, invB = 1.0f / lsB;
        const int mA = b * 2048 + qt * 64 + qh * 32 + qi;   // subtile A row
        #pragma unroll
        for (int dt = 0; dt < 4; ++dt) {
            us4 ta, tb;
            #pragma unroll
            for (int r = 0; r < 4; ++r) {
                ta[r] = bf16r(oA[dt][r] * invA);
                tb[r] = bf16r(oB[dt][r] * invB);
            }
            const int n0 = h * 64 + dt * 16 + g * 4;
            *(us4*)&ob[fragoff(mA,      n0, 8)] = ta;
            *(us4*)&ob[fragoff(mA + 16, n0, 8)] = tb;
        }
    }
}

// ---------------------------------------------------------------------------
// Launch
// ---------------------------------------------------------------------------
extern "C" void kernel_launch(void* const* d_in, const int* in_sizes, int n_in,
                              void* d_out, int out_size, void* d_ws, size_t ws_size,
                              hipStream_t stream) {
    const float* x      = (const float*)d_in[0];
    const int*   mask   = (const int*)  d_in[1];
    const float* bn1_g  = (const float*)d_in[2];
    const float* bn1_b  = (const float*)d_in[3];
    const float* bn1_m  = (const float*)d_in[4];
    const float* bn1_v  = (const float*)d_in[5];
    const float* qkv_w  = (const float*)d_in[6];
    const float* proj_w = (const float*)d_in[7];
    const float* bn2_g  = (const float*)d_in[8];
    const float* bn2_b  = (const float*)d_in[9];
    const float* bn2_m  = (const float*)d_in[10];
    const float* bn2_v  = (const float*)d_in[11];
    const float* w1     = (const float*)d_in[12];
    const float* w2     = (const float*)d_in[13];
    float* out = (float*)d_out;

    // workspace layout (bytes)
    char* w8 = (char*)d_ws;
    unsigned short* qkv_wf  = (unsigned short*)(w8 + 0);         // 384 KB
    unsigned short* proj_wf = (unsigned short*)(w8 + 393216);    // 128 KB
    unsigned short* w1f     = (unsigned short*)(w8 + 524288);    // 512 KB
    unsigned short* w2f     = (unsigned short*)(w8 + 1048576);   // 512 KB
    float*          maskf   = (float*)         (w8 + 1572864);   // 32 KB
    unsigned short* xbf     = (unsigned short*)(w8 + 2097152);   // 4 MB
    unsigned short* qfrag   = (unsigned short*)(w8 + 18874368);  // 4 MB
    unsigned short* kfrag   = (unsigned short*)(w8 + 23068672);  // 4 MB
    unsigned short* vfrag   = (unsigned short*)(w8 + 27262976);  // 4 MB
    unsigned short* ob      = (unsigned short*)(w8 + 31457280);  // 4 MB

    // fused prep (all weights + xb in frag order; mask)
    prep_all_k<<<2848, 256, 0, stream>>>(
        qkv_w, proj_w, w1, w2, qkv_wf, proj_wf, w1f, w2f,
        x, bn1_g, bn1_b, bn1_m, bn1_v, xbf, mask, maskf);

    // qkv = xbf @ qkv_wf -> qfrag/kfrag/vfrag; frag-streaming, 512 stripes
    gemm_qkv_frag_k<<<dim3(512), 512, 0, stream>>>(
        xbf, qkv_wf, qfrag, kfrag, vfrag);

    // attention -> ob (frag order); 512 blocks = 2/CU
    attn_mfma_k<<<dim3(512), 256, 0, stream>>>(qfrag, kfrag, vfrag, maskf, ob);

    // fused proj+BN2+mlp1+swish+mlp2+residual; 512 stripes, 8 waves
    fused_mlp_k<<<dim3(512), 512, 0, stream>>>(
        ob, proj_wf, w1f, w2f, x, bn2_g, bn2_b, bn2_m, bn2_v, out);
}

// Round 20
// 88.809 us; speedup vs baseline: 1.0225x; 1.0225x over previous
//
#include <hip/hip_runtime.h>
#include <math.h>

// Problem constants
#define S_ 2048
#define D_ 256
#define B_ 4
#define H_ 4
// M = B*S = 8192, DH = 64

typedef __attribute__((ext_vector_type(8))) short  bh8;   // 8 bf16 (4 VGPR)
typedef __attribute__((ext_vector_type(4))) float  fx4;
typedef __attribute__((ext_vector_type(4))) unsigned short us4;
typedef __attribute__((ext_vector_type(4))) unsigned int   ux4;

__device__ inline unsigned short bf16r(float f) {
    unsigned int u = __builtin_bit_cast(unsigned int, f);
    return (unsigned short)((u + 0x7FFFu + ((u >> 16) & 1u)) >> 16);
}
// v_cvt_pk_bf16_f32: src0 -> low bf16, src1 -> high bf16 (T12 recipe)
__device__ inline unsigned int cvtpk(float a, float b) {
    unsigned int r;
    asm("v_cvt_pk_bf16_f32 %0, %1, %2" : "=v"(r) : "v"(a), "v"(b));
    return r;
}
// raw hardware exp2 (scores bounded; masked -> exp2(-1e9) = 0 in HW).
// VOLATILE: R16 showed the scheduler hurts when free to reorder.
__device__ inline float vexp2(float x) {
    float r;
    asm volatile("v_exp_f32 %0, %1\n\ts_nop 1" : "=v"(r) : "v"(x));
    return r;
}
__device__ inline void gl_lds16(const unsigned short* g, unsigned short* l) {
    __builtin_amdgcn_global_load_lds(
        (const __attribute__((address_space(1))) unsigned int*)g,
        (__attribute__((address_space(3))) unsigned int*)l, 16, 0, 0);
}
// vmcnt(0) drain + barrier, compiler-fenced (orders gl_lds vs ds_read)
#define DRAIN_BARRIER() asm volatile("s_waitcnt vmcnt(0)\n\ts_barrier" ::: "memory")

// ---------------------------------------------------------------------------
// MFMA-fragment-order layout [verified R13-R15]. X[m][k] of [Mtot][K] at:
//   ((m/16)*K32 + k/32)*512 + (((k%32)/8)*16 + m%16)*8 + k%8,  K32 = K/32.
// One wave-load at (mtile*K32+kt)*512 + lane*8 fetches a 16x32 A/B fragment.
// ---------------------------------------------------------------------------
__device__ inline size_t fragoff(int m, int k, int K32) {
    return ((size_t)(m >> 4) * K32 + (k >> 5)) * 512
         + (size_t)((((k >> 3) & 3) * 16 + (m & 15)) * 8 + (k & 7));
}

// ---------------------------------------------------------------------------
// Fused prep: qkv_w -> bf16 [N][K] row-major (for LDS-staged GEMM);
// proj/w1/w2 -> bf16 FRAG order (for frag-streaming fused MLP);
// xb = bf16(BN1(x)) row-major; maskf.
// ---------------------------------------------------------------------------
__global__ __launch_bounds__(256) void prep_all_k(
    const float* __restrict__ qkv_w, const float* __restrict__ proj_w,
    const float* __restrict__ w1,    const float* __restrict__ w2,
    unsigned short* __restrict__ qkv_wt, unsigned short* __restrict__ proj_wf,
    unsigned short* __restrict__ w1f,    unsigned short* __restrict__ w2f,
    const float* __restrict__ x,
    const float* __restrict__ g1, const float* __restrict__ b1,
    const float* __restrict__ m1, const float* __restrict__ v1,
    unsigned short* __restrict__ xb,
    const int* __restrict__ mask, float* __restrict__ maskf)
{
    const int bidx = blockIdx.x;
    if (bidx < 768) {
        const float* W; unsigned short* Wt; int K, N, u0; bool frag;
        if (bidx < 192)      { W = qkv_w;  Wt = qkv_wt; K = 256;  N = 768;  u0 = bidx * 256;        frag = false; }
        else if (bidx < 256) { W = proj_w; Wt = proj_wf; K = 256;  N = 256;  u0 = (bidx - 192) * 256; frag = true; }
        else if (bidx < 512) { W = w1;     Wt = w1f;    K = 256;  N = 1024; u0 = (bidx - 256) * 256; frag = true; }
        else                 { W = w2;     Wt = w2f;    K = 1024; N = 256;  u0 = (bidx - 512) * 256; frag = true; }
        const int u = u0 + threadIdx.x;
        const int k4 = u / N, n = u % N;
        us4 tv;
        #pragma unroll
        for (int j = 0; j < 4; ++j) tv[j] = bf16r(W[(size_t)(k4 * 4 + j) * N + n]);
        if (frag) *(us4*)&Wt[fragoff(n, k4 * 4, K >> 5)] = tv;
        else      *(us4*)&Wt[(size_t)n * K + k4 * 4] = tv;
    } else if (bidx < 2816) {
        const int i = (bidx - 768) * 256 + threadIdx.x;   // us4 unit
        const int c4 = (i & 63) * 4;
        float4 xv = *(const float4*)&x[(size_t)i * 4];
        float vv[4] = {xv.x, xv.y, xv.z, xv.w};
        us4 tv;
        #pragma unroll
        for (int j = 0; j < 4; ++j) {
            int c = c4 + j;
            float s = g1[c] * rsqrtf(v1[c] + 1e-3f);
            tv[j] = bf16r(vv[j] * s + (b1[c] - m1[c] * s));
        }
        *(us4*)&xb[(size_t)i * 4] = tv;
    } else {
        const int i = (bidx - 2816) * 256 + threadIdx.x;
        maskf[i] = mask[i] ? 0.0f : -1e9f;
    }
}

// ---------------------------------------------------------------------------
// qkv GEMM, 2-phase double-buffered staging [FROZEN @ R12]. BM=64 x 128,
// BK=64, 4 waves. Epilogue -> frag-order qf/kf/vf (q scaled by log2e/16).
// ---------------------------------------------------------------------------
__global__ __launch_bounds__(256) void gemm_qkv_k(
    const unsigned short* __restrict__ A, const unsigned short* __restrict__ Wt,
    unsigned short* __restrict__ qf_o, unsigned short* __restrict__ kf_o,
    unsigned short* __restrict__ vf_o)
{
    constexpr int BM = 64, MI = 2, LA = 2;
    const int K = 256;
    __shared__ unsigned short Asb[2][BM * 64];
    __shared__ unsigned short Bsb[2][128 * 64];

    const int n0 = blockIdx.x * 128, m0 = blockIdx.y * BM;
    const int t = threadIdx.x, w = t >> 6, l = t & 63;
    const int qi = l & 15, g = l >> 4;
    const int wm = w >> 1, wn = w & 1;
    const int lr = l >> 3, lc = (l & 7) * 8;

    fx4 acc[MI][4];
    #pragma unroll
    for (int mi = 0; mi < MI; ++mi)
        #pragma unroll
        for (int ni = 0; ni < 4; ++ni) acc[mi][ni] = (fx4){0.f, 0.f, 0.f, 0.f};

    const int NT = K / 64;

#define STAGE(P, KT) {                                                        \
    const int kb = (KT) * 64;                                                 \
    _Pragma("unroll")                                                         \
    for (int i = 0; i < LA; ++i) {                                            \
        int r0 = (w * LA + i) * 8;                                            \
        gl_lds16(A + (size_t)(m0 + r0 + lr) * K + kb + lc, &Asb[P][r0 * 64]); \
    }                                                                         \
    _Pragma("unroll")                                                         \
    for (int i = 0; i < 4; ++i) {                                             \
        int r0 = (w * 4 + i) * 8;                                             \
        gl_lds16(Wt + (size_t)(n0 + r0 + lr) * K + kb + lc, &Bsb[P][r0 * 64]);\
    } }

    STAGE(0, 0);
    DRAIN_BARRIER();
    int p = 0;
    for (int kt = 0; kt < NT; ++kt) {
        if (kt + 1 < NT) STAGE(p ^ 1, kt + 1);
        #pragma unroll
        for (int kk = 0; kk < 2; ++kk) {
            bh8 af[MI], bf[4];
            #pragma unroll
            for (int mi = 0; mi < MI; ++mi)
                af[mi] = *(const bh8*)&Asb[p][(wm * (BM / 2) + mi * 16 + qi) * 64
                                             + kk * 32 + g * 8];
            #pragma unroll
            for (int ni = 0; ni < 4; ++ni)
                bf[ni] = *(const bh8*)&Bsb[p][(wn * 64 + ni * 16 + qi) * 64
                                             + kk * 32 + g * 8];
            #pragma unroll
            for (int mi = 0; mi < MI; ++mi)
                #pragma unroll
                for (int ni = 0; ni < 4; ++ni)
                    acc[mi][ni] = __builtin_amdgcn_mfma_f32_16x16x32_bf16(
                        af[mi], bf[ni], acc[mi][ni], 0, 0, 0);
        }
        DRAIN_BARRIER();
        p ^= 1;
    }
#undef STAGE

    const int mbase = m0 + wm * (BM / 2);
    #pragma unroll
    for (int ni = 0; ni < 4; ++ni) {
        const int nf = n0 + wn * 64 + ni * 16;
        const int h = nf / 192, rem = nf % 192;
        const int region = rem / 64;
        const int c = rem % 64 + qi;          // head-local column (dim)
        #pragma unroll
        for (int mi = 0; mi < MI; ++mi) {
            #pragma unroll
            for (int r = 0; r < 4; ++r) {
                const int m = mbase + mi * 16 + g * 4 + r;
                const int s = m & 2047;
                const size_t bh = (size_t)((m >> 11) * 4 + h);
                float a = acc[mi][ni][r];
                if (region < 2) {
                    size_t off = (((bh * 128 + (s >> 4)) * 2 + (c >> 5)) * 64
                                  + ((c >> 3) & 3) * 16 + (s & 15)) * 8 + (c & 7);
                    if (region == 0)
                        qf_o[off] = bf16r(a * (0.0625f * 1.44269504f));
                    else
                        kf_o[off] = bf16r(a);
                } else {
                    size_t off = ((((bh * 32 + (s >> 6)) * 4 + (c >> 4)) * 2
                                  + ((s >> 5) & 1)) * 64
                                  + ((s >> 3) & 3) * 16 + (c & 15)) * 8 + (s & 7);
                    vf_o[off] = bf16r(a);
                }
            }
        }
    }
}

// ---------------------------------------------------------------------------
// Fused MLP block: proj(+x residual, BN2) -> mlp1(swish) -> mlp2(+x2 resid).
// One block = one 16-row stripe (grid 512 = 2 blocks/CU), 8 waves.
// Wave w owns cols [w*32) for proj & mlp2, [w*128) for mlp1.
// x2 residual lives in REGISTERS; x2nb/h2 live in LDS in FRAG order
// (conflict-free lane*16B A-reads); weights stream from global in frag order.
// ---------------------------------------------------------------------------
__global__ __launch_bounds__(512) void fused_mlp_k(
    const unsigned short* __restrict__ ob,       // frag, A of proj (K32=8)
    const unsigned short* __restrict__ proj_wf,  // frag by n (K32=8)
    const unsigned short* __restrict__ w1f,      // frag by n (K32=8)
    const unsigned short* __restrict__ w2f,      // frag by n (K32=32)
    const float* __restrict__ x,
    const float* __restrict__ g2, const float* __restrict__ b2,
    const float* __restrict__ m2, const float* __restrict__ v2,
    float* __restrict__ out)
{
    __shared__ unsigned short x2nb[8 * 512];    // 16x256 bf16, frag order
    __shared__ unsigned short h2[32 * 512];     // 16x1024 bf16, frag order

    const int t = threadIdx.x, w = t >> 6, l = t & 63;
    const int qi = l & 15, g = l >> 4;
    const int mt = blockIdx.x;                  // 16-row stripe
    const int m0 = mt * 16;

    // ---- phase 1: proj (K=256, wave cols [w*32, w*32+32)) ----
    fx4 acc1[2];
    acc1[0] = (fx4){0.f, 0.f, 0.f, 0.f};
    acc1[1] = (fx4){0.f, 0.f, 0.f, 0.f};
    {
        const unsigned short* Ab = ob + (size_t)mt * 8 * 512 + l * 8;
        const unsigned short* B0 = proj_wf + ((size_t)(w * 2 + 0) * 8) * 512 + l * 8;
        const unsigned short* B1 = proj_wf + ((size_t)(w * 2 + 1) * 8) * 512 + l * 8;
        #pragma unroll
        for (int kt = 0; kt < 8; ++kt) {
            bh8 a  = *(const bh8*)(Ab + (size_t)kt * 512);
            bh8 b0 = *(const bh8*)(B0 + (size_t)kt * 512);
            bh8 b1 = *(const bh8*)(B1 + (size_t)kt * 512);
            acc1[0] = __builtin_amdgcn_mfma_f32_16x16x32_bf16(a, b0, acc1[0], 0, 0, 0);
            acc1[1] = __builtin_amdgcn_mfma_f32_16x16x32_bf16(a, b1, acc1[1], 0, 0, 0);
        }
    }
    float x2res[2][4];
    #pragma unroll
    for (int nt = 0; nt < 2; ++nt) {
        const int n = w * 32 + nt * 16 + qi;
        const float s2 = g2[n] * rsqrtf(v2[n] + 1e-3f);
        const float o2 = b2[n] - m2[n] * s2;
        #pragma unroll
        for (int r = 0; r < 4; ++r) {
            const int m = m0 + g * 4 + r;
            float rv = acc1[nt][r] + x[(size_t)m * 256 + n];
            x2res[nt][r] = rv;
            // frag write: kt = n/32 = w; lane' = (nt*2+(qi>>3))*16 + (g*4+r)
            x2nb[w * 512 + ((nt * 2 + (qi >> 3)) * 16 + g * 4 + r) * 8 + (qi & 7)]
                = bf16r(rv * s2 + o2);
        }
    }
    __syncthreads();

    // ---- phase 2: mlp1 (K=256, wave cols [w*128, w*128+128)) ----
    fx4 acc2[8];
    #pragma unroll
    for (int nt = 0; nt < 8; ++nt) acc2[nt] = (fx4){0.f, 0.f, 0.f, 0.f};
    {
        #pragma unroll
        for (int kt = 0; kt < 8; ++kt) {
            bh8 a = *(const bh8*)&x2nb[kt * 512 + l * 8];
            #pragma unroll
            for (int nt = 0; nt < 8; ++nt) {
                bh8 b = *(const bh8*)(w1f + ((size_t)(w * 8 + nt) * 8 + kt) * 512 + l * 8);
                acc2[nt] = __builtin_amdgcn_mfma_f32_16x16x32_bf16(a, b, acc2[nt], 0, 0, 0);
            }
        }
    }
    __syncthreads();   // all phase-2 x2nb reads done before... (x2nb dead now)
    #pragma unroll
    for (int nt = 0; nt < 8; ++nt) {
        #pragma unroll
        for (int r = 0; r < 4; ++r) {
            const int n = w * 128 + nt * 16 + qi;
            float a = acc2[nt][r];
            float hv = a / (1.0f + __expf(-a));
            h2[(n >> 5) * 512 + (((n >> 3) & 3) * 16 + g * 4 + r) * 8 + (n & 7)]
                = bf16r(hv);
        }
    }
    __syncthreads();

    // ---- phase 3: mlp2 (K=1024, wave cols [w*32, w*32+32)) ----
    fx4 acc3[2];
    acc3[0] = (fx4){0.f, 0.f, 0.f, 0.f};
    acc3[1] = (fx4){0.f, 0.f, 0.f, 0.f};
    {
        const unsigned short* B0 = w2f + ((size_t)(w * 2 + 0) * 32) * 512 + l * 8;
        const unsigned short* B1 = w2f + ((size_t)(w * 2 + 1) * 32) * 512 + l * 8;
        #pragma unroll 4
        for (int kt = 0; kt < 32; ++kt) {
            bh8 a  = *(const bh8*)&h2[kt * 512 + l * 8];
            bh8 b0 = *(const bh8*)(B0 + (size_t)kt * 512);
            bh8 b1 = *(const bh8*)(B1 + (size_t)kt * 512);
            acc3[0] = __builtin_amdgcn_mfma_f32_16x16x32_bf16(a, b0, acc3[0], 0, 0, 0);
            acc3[1] = __builtin_amdgcn_mfma_f32_16x16x32_bf16(a, b1, acc3[1], 0, 0, 0);
        }
    }
    #pragma unroll
    for (int nt = 0; nt < 2; ++nt) {
        #pragma unroll
        for (int r = 0; r < 4; ++r) {
            const int m = m0 + g * 4 + r;
            const int n = w * 32 + nt * 16 + qi;
            out[(size_t)m * 256 + n] = acc3[nt][r] + x2res[nt][r];
        }
    }
}

// ---------------------------------------------------------------------------
// MFMA flash attention [FROZEN @ R14/R18, 43.0 us]: 2 Q-subtiles per wave,
// 2-way key split, volatile vexp2 fixed-max softmax, frag Q/K/V, frag ob.
// Grid 512: bid&15 = (b,h) -> XCD-local KV.
// ---------------------------------------------------------------------------
__global__ __launch_bounds__(256) void attn_mfma_k(
    const unsigned short* __restrict__ qf,
    const unsigned short* __restrict__ kf,
    const unsigned short* __restrict__ vf,
    const float* __restrict__ maskf,
    unsigned short* __restrict__ ob)
{
    __shared__ fx4  Ol[2][64][8];
    __shared__ float Ll[2][64][2];

    const int bid = blockIdx.x;
    const int bh = bid & 15, qt = bid >> 4;        // qt in [0,32): 64 q-rows
    const int b = bh >> 2, h = bh & 3;
    const int t = threadIdx.x;
    const int w = t >> 6, lane = t & 63;
    const int g = lane >> 4, qi = lane & 15;
    const int qh = w & 1;                          // 32-row group within block
    const int khalf = w >> 1;                      // key half

    bh8 qA0, qA1, qB0, qB1;
    {
        const unsigned short* qp =
            qf + (size_t)(bh * 128 + qt * 4 + qh * 2) * 1024 + lane * 8;
        qA0 = *(const bh8*)(qp);
        qA1 = *(const bh8*)(qp + 512);
        qB0 = *(const bh8*)(qp + 1024);
        qB1 = *(const bh8*)(qp + 1536);
    }

    fx4 oA[4], oB[4];
    #pragma unroll
    for (int dt = 0; dt < 4; ++dt) {
        oA[dt] = (fx4){0.f, 0.f, 0.f, 0.f};
        oB[dt] = (fx4){0.f, 0.f, 0.f, 0.f};
    }
    float lsA = 0.f, lsB = 0.f;

    const unsigned short* kcur = kf + (size_t)bh * 131072 + khalf * 65536 + lane * 8;
    const unsigned short* vcur = vf + (size_t)bh * 131072 + khalf * 65536 + lane * 8;
    const float* mcur = maskf + b * 2048 + khalf * 1024 + g * 4;

    bh8 kfA[4][2], kfB[4][2], afA[4][2], afB[4][2];
    fx4 mvA[4], mvB[4];

#define LOADK(KF, MV) {                                                       \
    KF[0][0] = *(const bh8*)(kcur);        KF[0][1] = *(const bh8*)(kcur + 512);  \
    KF[1][0] = *(const bh8*)(kcur + 1024); KF[1][1] = *(const bh8*)(kcur + 1536); \
    KF[2][0] = *(const bh8*)(kcur + 2048); KF[2][1] = *(const bh8*)(kcur + 2560); \
    KF[3][0] = *(const bh8*)(kcur + 3072); KF[3][1] = *(const bh8*)(kcur + 3584); \
    MV[0] = *(const fx4*)(mcur);      MV[1] = *(const fx4*)(mcur + 16);       \
    MV[2] = *(const fx4*)(mcur + 32); MV[3] = *(const fx4*)(mcur + 48);       \
    kcur += 4096; mcur += 64; }

#define LOADV(AF) {                                                           \
    AF[0][0] = *(const bh8*)(vcur);        AF[0][1] = *(const bh8*)(vcur + 512);  \
    AF[1][0] = *(const bh8*)(vcur + 1024); AF[1][1] = *(const bh8*)(vcur + 1536); \
    AF[2][0] = *(const bh8*)(vcur + 2048); AF[2][1] = *(const bh8*)(vcur + 2560); \
    AF[3][0] = *(const bh8*)(vcur + 3072); AF[3][1] = *(const bh8*)(vcur + 3584); \
    vcur += 4096; }

#define PROCESS(KF, AF, MV) {                                                 \
    fx4 sA[4], sB[4];                                                         \
    _Pragma("unroll")                                                         \
    for (int kt = 0; kt < 4; ++kt) {                                          \
        fx4 zA = MV[kt];                                                      \
        zA = __builtin_amdgcn_mfma_f32_16x16x32_bf16(KF[kt][0], qA0, zA, 0, 0, 0); \
        zA = __builtin_amdgcn_mfma_f32_16x16x32_bf16(KF[kt][1], qA1, zA, 0, 0, 0); \
        sA[kt] = zA;                                                          \
        fx4 zB = MV[kt];                                                      \
        zB = __builtin_amdgcn_mfma_f32_16x16x32_bf16(KF[kt][0], qB0, zB, 0, 0, 0); \
        zB = __builtin_amdgcn_mfma_f32_16x16x32_bf16(KF[kt][1], qB1, zB, 0, 0, 0); \
        sB[kt] = zB;                                                          \
    }                                                                         \
    unsigned int pkA[4][2], pkB[4][2];                                        \
    _Pragma("unroll")                                                         \
    for (int kt = 0; kt < 4; ++kt) {                                          \
        float a0 = vexp2(sA[kt][0]);                                          \
        float a1 = vexp2(sA[kt][1]);                                          \
        float a2 = vexp2(sA[kt][2]);                                          \
        float a3 = vexp2(sA[kt][3]);                                          \
        lsA += (a0 + a1) + (a2 + a3);                                         \
        pkA[kt][0] = cvtpk(a0, a1);                                           \
        pkA[kt][1] = cvtpk(a2, a3);                                           \
        float b0 = vexp2(sB[kt][0]);                                          \
        float b1 = vexp2(sB[kt][1]);                                          \
        float b2 = vexp2(sB[kt][2]);                                          \
        float b3 = vexp2(sB[kt][3]);                                          \
        lsB += (b0 + b1) + (b2 + b3);                                         \
        pkB[kt][0] = cvtpk(b0, b1);                                           \
        pkB[kt][1] = cvtpk(b2, b3);                                           \
    }                                                                         \
    _Pragma("unroll")                                                         \
    for (int c = 0; c < 2; ++c) {                                             \
        unsigned int bwA[4], bwB[4];                                          \
        _Pragma("unroll")                                                     \
        for (int wd = 0; wd < 4; ++wd) {                                      \
            int src = (2 * (g & 1) + (wd >> 1)) * 16 + qi;                    \
            unsigned int vaA = (unsigned int)__shfl((int)pkA[2 * c][wd & 1], src, 64);     \
            unsigned int vbA = (unsigned int)__shfl((int)pkA[2 * c + 1][wd & 1], src, 64); \
            bwA[wd] = (g >= 2) ? vbA : vaA;                                   \
            unsigned int vaB = (unsigned int)__shfl((int)pkB[2 * c][wd & 1], src, 64);     \
            unsigned int vbB = (unsigned int)__shfl((int)pkB[2 * c + 1][wd & 1], src, 64); \
            bwB[wd] = (g >= 2) ? vbB : vaB;                                   \
        }                                                                     \
        bh8 bfA = __builtin_bit_cast(bh8, (ux4){bwA[0], bwA[1], bwA[2], bwA[3]}); \
        bh8 bfB = __builtin_bit_cast(bh8, (ux4){bwB[0], bwB[1], bwB[2], bwB[3]}); \
        _Pragma("unroll")                                                     \
        for (int dt = 0; dt < 4; ++dt) {                                      \
            oA[dt] = __builtin_amdgcn_mfma_f32_16x16x32_bf16(AF[dt][c], bfA, oA[dt], 0, 0, 0); \
            oB[dt] = __builtin_amdgcn_mfma_f32_16x16x32_bf16(AF[dt][c], bfB, oB[dt], 0, 0, 0); \
        }                                                                     \
    } }

    LOADK(kfA, mvA);
    LOADV(afA);
    for (int it = 0; it < 16; it += 2) {
        LOADK(kfB, mvB);
        LOADV(afB);
        PROCESS(kfA, afA, mvA);
        if (it + 2 < 16) {
            LOADK(kfA, mvA);
            LOADV(afA);
        }
        PROCESS(kfB, afB, mvB);
    }
#undef LOADK
#undef LOADV
#undef PROCESS

    // ---- combine key-halves: waves 2,3 publish; waves 0,1 add + write
    const int slot = w & 1;
    if (w >= 2) {
        #pragma unroll
        for (int dt = 0; dt < 4; ++dt) {
            Ol[slot][lane][dt]     = oA[dt];
            Ol[slot][lane][4 + dt] = oB[dt];
        }
        Ll[slot][lane][0] = lsA;
        Ll[slot][lane][1] = lsB;
    }
    __syncthreads();
    if (w < 2) {
        lsA += Ll[slot][lane][0];
        lsB += Ll[slot][lane][1];
        #pragma unroll
        for (int dt = 0; dt < 4; ++dt) {
            fx4 pa = Ol[slot][lane][dt], pb = Ol[slot][lane][4 + dt];
            oA[dt][0] += pa[0]; oA[dt][1] += pa[1]; oA[dt][2] += pa[2]; oA[dt][3] += pa[3];
            oB[dt][0] += pb[0]; oB[dt][1] += pb[1]; oB[dt][2] += pb[2]; oB[dt][3] += pb[3];
        }
        lsA += __shfl_xor(lsA, 16, 64);
        lsA += __shfl_xor(lsA, 32, 64);
        lsB += __shfl_xor(lsB, 16, 64);
        lsB += __shfl_xor(lsB, 32, 64);
        float invA = 1.0f / lsA, invB = 1.0f / lsB;
        const int mA = b * 2048 + qt * 64 + qh * 32 + qi;   // subtile A row
        #pragma unroll
        for (int dt = 0; dt < 4; ++dt) {
            us4 ta, tb;
            #pragma unroll
            for (int r = 0; r < 4; ++r) {
                ta[r] = bf16r(oA[dt][r] * invA);
                tb[r] = bf16r(oB[dt][r] * invB);
            }
            const int n0 = h * 64 + dt * 16 + g * 4;
            *(us4*)&ob[fragoff(mA,      n0, 8)] = ta;
            *(us4*)&ob[fragoff(mA + 16, n0, 8)] = tb;
        }
    }
}

// ---------------------------------------------------------------------------
// Launch
// ---------------------------------------------------------------------------
extern "C" void kernel_launch(void* const* d_in, const int* in_sizes, int n_in,
                              void* d_out, int out_size, void* d_ws, size_t ws_size,
                              hipStream_t stream) {
    const float* x      = (const float*)d_in[0];
    const int*   mask   = (const int*)  d_in[1];
    const float* bn1_g  = (const float*)d_in[2];
    const float* bn1_b  = (const float*)d_in[3];
    const float* bn1_m  = (const float*)d_in[4];
    const float* bn1_v  = (const float*)d_in[5];
    const float* qkv_w  = (const float*)d_in[6];
    const float* proj_w = (const float*)d_in[7];
    const float* bn2_g  = (const float*)d_in[8];
    const float* bn2_b  = (const float*)d_in[9];
    const float* bn2_m  = (const float*)d_in[10];
    const float* bn2_v  = (const float*)d_in[11];
    const float* w1     = (const float*)d_in[12];
    const float* w2     = (const float*)d_in[13];
    float* out = (float*)d_out;

    // workspace layout (bytes)
    char* w8 = (char*)d_ws;
    unsigned short* qkv_wt  = (unsigned short*)(w8 + 0);         // 384 KB
    unsigned short* proj_wf = (unsigned short*)(w8 + 393216);    // 128 KB
    unsigned short* w1f     = (unsigned short*)(w8 + 524288);    // 512 KB
    unsigned short* w2f     = (unsigned short*)(w8 + 1048576);   // 512 KB
    float*          maskf   = (float*)         (w8 + 1572864);   // 32 KB
    unsigned short* xb      = (unsigned short*)(w8 + 2097152);   // 4 MB
    unsigned short* qfrag   = (unsigned short*)(w8 + 18874368);  // 4 MB
    unsigned short* kfrag   = (unsigned short*)(w8 + 23068672);  // 4 MB
    unsigned short* vfrag   = (unsigned short*)(w8 + 27262976);  // 4 MB
    unsigned short* ob      = (unsigned short*)(w8 + 31457280);  // 4 MB

    // fused prep (qkv_wt row-major; proj/w1/w2 frag; xb; mask)
    prep_all_k<<<2848, 256, 0, stream>>>(
        qkv_w, proj_w, w1, w2, qkv_wt, proj_wf, w1f, w2f,
        x, bn1_g, bn1_b, bn1_m, bn1_v, xb, mask, maskf);

    // qkv = xb @ qkv_wt -> qfrag/kfrag/vfrag; BM=64, 768 blocks = 3/CU
    gemm_qkv_k<<<dim3(6, 128), 256, 0, stream>>>(
        xb, qkv_wt, qfrag, kfrag, vfrag);

    // attention -> ob (frag order); 512 blocks = 2/CU
    attn_mfma_k<<<dim3(512), 256, 0, stream>>>(qfrag, kfrag, vfrag, maskf, ob);

    // fused proj+BN2+mlp1+swish+mlp2+residual; 512 stripes = 2/CU, 8 waves
    fused_mlp_k<<<dim3(512), 512, 0, stream>>>(
        ob, proj_wf, w1f, w2f, x, bn2_g, bn2_b, bn2_m, bn2_v, out);
}